// Round 10
// baseline (444.635 us; speedup 1.0000x reference)
//
#include <hip/hip_runtime.h>
#include <math.h>

#define BSZ 2
#define SEQ 2048
#define DIM 1024
#define NH 16
#define HDIM 64
#define MR (BSZ*SEQ)   // 4096 rows

typedef __attribute__((ext_vector_type(8))) short bf16x8;
typedef __attribute__((ext_vector_type(4))) short bf16x4;
typedef __attribute__((ext_vector_type(4))) float floatx4;
typedef _Float16 f16x8 __attribute__((ext_vector_type(8)));

static __device__ __forceinline__ unsigned short f2bf(float x) {
    unsigned u = __float_as_uint(x);
    u += 0x7fffu + ((u >> 16) & 1u);
    return (unsigned short)(u >> 16);
}
static __device__ __forceinline__ float bf2f(unsigned short h) {
    return __uint_as_float(((unsigned)h) << 16);
}
static __device__ __forceinline__ unsigned short f2h(float x) {
    union { _Float16 h; unsigned short u; } v;
    v.h = (_Float16)x;
    return v.u;
}
// raw v_exp_f32 (exp2) — exp2f() is an OCML libcall with range fixups (VALU-heavy)
static __device__ __forceinline__ float fexp2(float x) {
#if __has_builtin(__builtin_amdgcn_exp2f)
    return __builtin_amdgcn_exp2f(x);
#else
    return __expf(x * 0.69314718055994531f);
#endif
}
// pack 4 f32 -> bf16x4 via v_cvt_pk_bf16_f32 (RNE), 2 VALU insts vs ~16 manual
static __device__ __forceinline__ bf16x4 pack_bf16x4(float a, float b, float c, float d) {
    union { unsigned u[2]; bf16x4 v; } r;
    asm("v_cvt_pk_bf16_f32 %0, %1, %2" : "=v"(r.u[0]) : "v"(a), "v"(b));
    asm("v_cvt_pk_bf16_f32 %0, %1, %2" : "=v"(r.u[1]) : "v"(c), "v"(d));
    return r.v;
}
#define MFMA16(a,b,c) __builtin_amdgcn_mfma_f32_16x16x32_bf16((a),(b),(c),0,0,0)

static __device__ __forceinline__ floatx4 mfma_f16(bf16x8 a, bf16x8 b, floatx4 c) {
    union { bf16x8 s; f16x8 h; } ua, ub;
    ua.s = a; ub.s = b;
    return __builtin_amdgcn_mfma_f32_16x16x32_f16(ua.h, ub.h, c, 0, 0, 0);
}

// 16x16x16 bf16 MFMA (K=16): A,B = 4 bf16/lane at k=quad*4+j.
static __device__ __forceinline__ floatx4 pv_mfma(bf16x4 a, bf16x4 b, floatx4 c) {
#if __has_builtin(__builtin_amdgcn_mfma_f32_16x16x16bf16_1k)
    return __builtin_amdgcn_mfma_f32_16x16x16bf16_1k(a, b, c, 0, 0, 0);
#else
    bf16x8 a8 = {a[0],a[1],a[2],a[3],0,0,0,0};
    bf16x8 b8 = {b[0],b[1],b[2],b[3],0,0,0,0};
    return MFMA16(a8, b8, c);
#endif
}

// async global -> LDS, 16 B per lane. LDS dest = wave-uniform base + lane*16.
static __device__ __forceinline__ void gld16(const void* g, void* l) {
    __builtin_amdgcn_global_load_lds(
        (const __attribute__((address_space(1))) void*)g,
        (__attribute__((address_space(3))) void*)l, 16, 0, 0);
}

// ---------------------------------------------------------------------------
// conv_split: fp32 [rows][1024] -> bf16 [rows][2048] as [hi | lo]
// ---------------------------------------------------------------------------
__global__ __launch_bounds__(256)
void conv_split(const float* p0, const float* p1, const float* p2,
                const float* p3,
                unsigned short* o0, unsigned short* o1, unsigned short* o2,
                unsigned short* o3,
                int r0, int r1, int r2, int r3)
{
    const float* pin; unsigned short* pout; int rows;
    switch (blockIdx.y) {
        case 0: pin=p0; pout=o0; rows=r0; break;
        case 1: pin=p1; pout=o1; rows=r1; break;
        case 2: pin=p2; pout=o2; rows=r2; break;
        default: pin=p3; pout=o3; rows=r3; break;
    }
    size_t idx = (size_t)blockIdx.x * 256 + threadIdx.x;   // group of 4 floats
    if (idx * 4 >= (size_t)rows * DIM) return;
    size_t row = (idx * 4) >> 10;
    int col = (int)((idx * 4) & 1023);
    float4 f = *(const float4*)(pin + idx * 4);
    ushort4 h, l;
    h.x = f2bf(f.x); l.x = f2bf(f.x - bf2f(h.x));
    h.y = f2bf(f.y); l.y = f2bf(f.y - bf2f(h.y));
    h.z = f2bf(f.z); l.z = f2bf(f.z - bf2f(h.z));
    h.w = f2bf(f.w); l.w = f2bf(f.w - bf2f(h.w));
    *(ushort4*)(pout + row * 2048 + col)        = h;
    *(ushort4*)(pout + row * 2048 + 1024 + col) = l;
}

// conv_f16: fp32 flat -> fp16 flat, 4 matrices via blockIdx.y
__global__ __launch_bounds__(256)
void conv_f16(const float* p0, const float* p1, const float* p2, const float* p3,
              unsigned short* o0, unsigned short* o1, unsigned short* o2,
              unsigned short* o3, int r0, int r1, int r2, int r3)
{
    const float* pin; unsigned short* pout; int rows;
    switch (blockIdx.y) {
        case 0: pin=p0; pout=o0; rows=r0; break;
        case 1: pin=p1; pout=o1; rows=r1; break;
        case 2: pin=p2; pout=o2; rows=r2; break;
        default: pin=p3; pout=o3; rows=r3; break;
    }
    size_t idx = (size_t)blockIdx.x * 256 + threadIdx.x;
    if (idx * 4 >= (size_t)rows * DIM) return;
    float4 f = *(const float4*)(pin + idx * 4);
    ushort4 h;
    h.x = f2h(f.x); h.y = f2h(f.y); h.z = f2h(f.z); h.w = f2h(f.w);
    *(ushort4*)(pout + idx * 4) = h;
}

// conv_hi: fp32 flat -> bf16 flat (hi only), 3 matrices via blockIdx.y
__global__ __launch_bounds__(256)
void conv_hi(const float* p0, const float* p1, const float* p2,
             unsigned short* o0, unsigned short* o1, unsigned short* o2,
             int n0, int n1, int n2)
{
    const float* pin; unsigned short* pout; int n;
    switch (blockIdx.y) {
        case 0: pin=p0; pout=o0; n=n0; break;
        case 1: pin=p1; pout=o1; n=n1; break;
        default: pin=p2; pout=o2; n=n2; break;
    }
    size_t idx = (size_t)blockIdx.x * 256 + threadIdx.x;
    if (idx * 4 >= (size_t)n) return;
    float4 f = *(const float4*)(pin + idx * 4);
    ushort4 h;
    h.x = f2bf(f.x); h.y = f2bf(f.y); h.z = f2bf(f.z); h.w = f2bf(f.w);
    *(ushort4*)(pout + idx * 4) = h;
}

// ---------------------------------------------------------------------------
// MFMA GEMM — m97-style: global_load_lds staging into linear LDS [128][64],
// two barriers per K-step (the second's implicit vmcnt(0) drains the DMA).
// No reg-staging, no ds_writes (ladder m93->m97: +69%).
// DT: 0 = bf16 MFMA, 1 = fp16 MFMA.
// EPI: 0 = fp32 row-major [.][1024]
//      1 = split-bf16 per-(b,h): out[bh][s][0..63 hi | 64..127 lo],
//          16B-chunk XOR-swizzled by (s&7)   <-- for flash global_load_lds
//      2 = V^T per-(b,h): out[bh][d][s] (bf16), 16B-chunk swizzled by (d&7)
//      3 = fp16 per-(b,h): out[bh][s][d] (fp16)
// ---------------------------------------------------------------------------
template<int EPI, bool SPLIT3, int DT>
__global__ __launch_bounds__(256)
void gemm_mfma(const unsigned short* __restrict__ A0, const unsigned short* __restrict__ A1,
               const unsigned short* __restrict__ B0, const unsigned short* __restrict__ B1,
               void* C0v, void* C1v, int lda, int ldb, int nkb)
{
    const unsigned short* A = blockIdx.z ? A1 : A0;
    const unsigned short* B = blockIdx.z ? B1 : B0;
    float* Cf = (float*)(blockIdx.z ? C1v : C0v);
    unsigned short* Cb = (unsigned short*)(blockIdx.z ? C1v : C0v);

    __shared__ __align__(16) unsigned short As[128][64];   // 16 KB, linear
    __shared__ __align__(16) unsigned short Bs[128][64];   // 16 KB, linear

    const int tid = threadIdx.x;
    const int lane = tid & 63, wv = tid >> 6;
    const int c = lane & 15, quad = lane >> 4;
    const int wm = wv >> 1, wn = wv & 1;
    const int rowBase = blockIdx.y << 7;
    const int colBase = blockIdx.x << 7;

    floatx4 acc[4][4];
#pragma unroll
    for (int i = 0; i < 4; ++i)
#pragma unroll
        for (int j = 0; j < 4; ++j) acc[i][j] = (floatx4){0.f,0.f,0.f,0.f};

    for (int kb = 0; kb < nkb; ++kb) {
        int aoff, boff;
        if (SPLIT3) {
            int t = kb >> 4, kk = (kb & 15) << 6;
            aoff = ((t == 1) ? 1024 : 0) + kk;
            boff = ((t == 2) ? 1024 : 0) + kk;
        } else { aoff = boff = kb << 6; }
        __syncthreads();   // all waves done reading previous tile
#pragma unroll
        for (int i = 0; i < 4; ++i) {
            int f = tid + (i << 8);
            int r = f >> 3, ch = (f & 7) << 3;
            gld16(A + (size_t)(rowBase + r) * lda + aoff + ch,
                  &As[0][0] + (size_t)f * 8);
            gld16(B + (size_t)(colBase + r) * ldb + boff + ch,
                  &Bs[0][0] + (size_t)f * 8);
        }
        __syncthreads();   // implicit vmcnt(0): all DMA landed, visible to all
#pragma unroll
        for (int ks = 0; ks < 2; ++ks) {
            bf16x8 af[4], bfr[4];
#pragma unroll
            for (int i = 0; i < 4; ++i) {
                af[i]  = *(const bf16x8*)&As[wm*64 + i*16 + c][ks*32 + quad*8];
                bfr[i] = *(const bf16x8*)&Bs[wn*64 + i*16 + c][ks*32 + quad*8];
            }
#pragma unroll
            for (int mi = 0; mi < 4; ++mi)
#pragma unroll
                for (int ni = 0; ni < 4; ++ni) {
                    if (DT == 0) acc[mi][ni] = MFMA16(af[mi], bfr[ni], acc[mi][ni]);
                    else         acc[mi][ni] = mfma_f16(af[mi], bfr[ni], acc[mi][ni]);
                }
        }
    }
    const int row0 = rowBase + wm*64 + quad*4;
    if (EPI == 0) {
        const int col0 = colBase + wn*64 + c;
#pragma unroll
        for (int mi = 0; mi < 4; ++mi)
#pragma unroll
            for (int r = 0; r < 4; ++r) {
                size_t ro = (size_t)(row0 + mi*16 + r) * 1024 + col0;
#pragma unroll
                for (int ni = 0; ni < 4; ++ni)
                    Cf[ro + ni*16] = acc[mi][ni][r];
            }
    } else if (EPI == 1) {
        const int h = (colBase >> 6) + wn;       // head index
#pragma unroll
        for (int mi = 0; mi < 4; ++mi)
#pragma unroll
            for (int r = 0; r < 4; ++r) {
                int row = row0 + mi*16 + r;
                int b = row >> 11, s = row & 2047;
                size_t base = ((size_t)((b<<4) | h) * 2048 + s) * 128;
                const int sw = (s & 7) << 3;     // chunk-XOR in element units
#pragma unroll
                for (int ni = 0; ni < 4; ++ni) {
                    int d = ni*16 + c;
                    int dsw = d ^ sw;            // swizzled hi position (bit6 untouched)
                    float x = acc[mi][ni][r];
                    unsigned short hb = f2bf(x);
                    Cb[base + dsw]      = hb;
                    Cb[base + 64 + dsw] = f2bf(x - bf2f(hb));
                }
            }
    } else if (EPI == 2) {  // Vt[bh][d][s], 16B chunks along s swizzled by (d&7)
        const int h = (colBase >> 6) + wn;
#pragma unroll
        for (int mi = 0; mi < 4; ++mi) {
            int row = row0 + mi*16;
            int b = row >> 11, s = row & 2047;
#pragma unroll
            for (int ni = 0; ni < 4; ++ni) {
                int d = ni*16 + c;
                int scol = s ^ ((d & 7) << 3);   // s%8 in {0,4}: stays inside chunk
                size_t base = ((size_t)((b<<4)|h) * 64 + d) * 2048 + scol;
                ushort4 o4;
                o4.x = f2bf(acc[mi][ni][0]); o4.y = f2bf(acc[mi][ni][1]);
                o4.z = f2bf(acc[mi][ni][2]); o4.w = f2bf(acc[mi][ni][3]);
                *(ushort4*)(Cb + base) = o4;
            }
        }
    } else {  // EPI == 3: fp16 per-bh [bh][s][64]
        const int h = (colBase >> 6) + wn;
#pragma unroll
        for (int mi = 0; mi < 4; ++mi)
#pragma unroll
            for (int r = 0; r < 4; ++r) {
                int row = row0 + mi*16 + r;
                int b = row >> 11, s = row & 2047;
                size_t base = ((size_t)((b<<4) | h) * 2048 + s) * 64;
#pragma unroll
                for (int ni = 0; ni < 4; ++ni)
                    Cb[base + ni*16 + c] = f2h(acc[mi][ni][r]);
            }
    }
}

// ---------------------------------------------------------------------------
// def_w, fp16: qd/kd are [bh][s][64] fp16. 512 threads / 8 waves, 16 q-rows
// per wave (round-6 flash occupancy transform: 4 waves/SIMD covers the
// sigmoid VALU chain). Writes def_w * 0.125 * log2(e).
// ---------------------------------------------------------------------------
__global__ __launch_bounds__(512)
void defw_mfma(const unsigned short* __restrict__ qd,
               const unsigned short* __restrict__ kd,
               float* __restrict__ defw)
{
    __shared__ __align__(16) unsigned short Ks[64][72];
    const int tid = threadIdx.x;
    const int wv = tid >> 6, lane = tid & 63;
    const int c = lane & 15, quad = lane >> 4;
    const int bh = blockIdx.y;
    const int qbase = blockIdx.x << 7;
    const int trow = tid >> 3, seg = tid & 7;   // 64 rows x 8 chunks

    bf16x8 qf[2];
    {
        const unsigned short* qrow =
            qd + ((size_t)bh*2048 + qbase + wv*16 + c)*64 + quad*8;
        qf[0] = *(const bf16x8*)(qrow);
        qf[1] = *(const bf16x8*)(qrow + 32);
    }
    float rs[4] = {0.f,0.f,0.f,0.f};
    const unsigned short* kbase = kd + (size_t)bh*2048*64;
    bf16x8 kpre = *(const bf16x8*)(kbase + (size_t)trow*64 + seg*8);
    for (int kt = 0; kt < SEQ; kt += 64) {
        __syncthreads();
        *(bf16x8*)&Ks[trow][seg*8] = kpre;
        __syncthreads();
        if (kt + 64 < SEQ)
            kpre = *(const bf16x8*)(kbase + (size_t)(kt + 64 + trow)*64 + seg*8);
#pragma unroll
        for (int nk = 0; nk < 4; ++nk) {
            const unsigned short* kr = &Ks[16*nk + c][quad*8];
            bf16x8 k0 = *(const bf16x8*)(kr);
            bf16x8 k1 = *(const bf16x8*)(kr + 32);
            floatx4 s = {0.f,0.f,0.f,0.f};
            s = mfma_f16(qf[0], k0, s);
            s = mfma_f16(qf[1], k1, s);
#pragma unroll
            for (int r = 0; r < 4; ++r)
                rs[r] += 1.f / (1.f + __expf(-0.125f * s[r]));
        }
    }
#pragma unroll
    for (int r = 0; r < 4; ++r) {
        float vv = rs[r];
        vv += __shfl_xor(vv, 1, 16);
        vv += __shfl_xor(vv, 2, 16);
        vv += __shfl_xor(vv, 4, 16);
        vv += __shfl_xor(vv, 8, 16);
        if (c == 0)
            defw[(size_t)bh*SEQ + qbase + wv*16 + 4*quad + r]
                = vv * 0.18033688011112042f;   // 0.125 * log2(e)
    }
}

// ---------------------------------------------------------------------------
// Flash attention (verified round-8: 99.2 us): 8 waves / 512 threads,
// 16 q-rows/wave. K/V via global_load_lds double-buffered, counted vmcnt(3),
// x2-unrolled K-loop with compile-time buffer index, setprio around MFMA.
// ---------------------------------------------------------------------------
__global__ __launch_bounds__(512)
void flash_mfma(const unsigned short* __restrict__ q,
                const unsigned short* __restrict__ kk,
                const unsigned short* __restrict__ vt,
                const float* __restrict__ dwg,
                unsigned short* __restrict__ o)
{
    __shared__ __align__(16) unsigned short Ks[2][64][128];  // 32 KB
    __shared__ __align__(16) unsigned short Vs[2][64][64];   // 16 KB
    __shared__ __align__(16) float dwL[SEQ];                 //  8 KB
    const int tid = threadIdx.x;
    const int wv = tid >> 6, lane = tid & 63;
    const int c = lane & 15, quad = lane >> 4;
    const int cswz = c & 7;
    const int bh = blockIdx.y, b = bh >> 4, h = bh & 15;
    const int qbase = blockIdx.x << 7;

    const unsigned short* kbase = kk + (size_t)bh*2048*128;
    const unsigned short* vbase = vt + (size_t)bh*64*2048;

    // ---- prologue: Q fragments (swizzled global layout), 16 rows/wave ----
    bf16x8 qhi[2], qlo[2];
    {
        const unsigned short* qrow =
            q + ((size_t)bh*2048 + qbase + wv*16 + c)*128;
        qhi[0] = *(const bf16x8*)(qrow + (((quad     ) ^ cswz) << 3));
        qhi[1] = *(const bf16x8*)(qrow + (((quad +  4) ^ cswz) << 3));
        qlo[0] = *(const bf16x8*)(qrow + (((quad +  8) ^ cswz) << 3));
        qlo[1] = *(const bf16x8*)(qrow + (((quad + 12) ^ cswz) << 3));
    }
    // dw row -> LDS (512 thr x 16B = 8 KB, 1 DMA inst / thread)
    gld16(dwg + (size_t)bh*SEQ + (size_t)tid*4, &dwL[(wv*64) * 4]);
    // tile 0 -> buffer 0 (K: 2/thread, V: 1/thread)
#pragma unroll
    for (int i = 0; i < 2; ++i) {
        int flat = tid + (i << 9);
        int r = flat >> 4, ch = flat & 15;
        gld16(kbase + (size_t)r*128 + (ch << 3),
              &Ks[0][0][0] + ((wv*64 + (i << 9)) << 3));
    }
    {
        int d = tid >> 3, ch = tid & 7;
        gld16(vbase + (size_t)d*2048 + (ch << 3),
              &Vs[0][0][0] + (wv*64 << 3));
    }

    floatx4 Oa[4];    // [nd], O^T[d][s]
#pragma unroll
    for (int nd = 0; nd < 4; ++nd) Oa[nd] = (floatx4){0.f,0.f,0.f,0.f};
    float mrun = -3.0e38f, lrun = 0.f;

// One 64-row K/V tile with compile-time buffer index CUR.
// PF: prefetch next tile into buffer CUR^1 (counted vmcnt keeps the 3 new
// loads in flight; vmcnt(3) drains the PREVIOUS tile's 3).
#define FLASH_TILE(CUR, KT, PF)                                               \
    {                                                                         \
        __builtin_amdgcn_s_barrier();                                         \
        if (PF) {                                                             \
            _Pragma("unroll")                                                 \
            for (int i = 0; i < 2; ++i) {                                     \
                int flat = tid + (i << 9);                                    \
                int r = flat >> 4, ch = flat & 15;                            \
                gld16(kbase + (size_t)((KT) + 64 + r)*128 + (ch << 3),        \
                      &Ks[(CUR)^1][0][0] + ((wv*64 + (i << 9)) << 3));        \
            }                                                                 \
            {                                                                 \
                int d = tid >> 3, ch = tid & 7;                               \
                gld16(vbase + (size_t)d*2048 + ((KT) + 64) + (ch << 3),       \
                      &Vs[(CUR)^1][0][0] + (wv*64 << 3));                     \
            }                                                                 \
            asm volatile("s_waitcnt vmcnt(3)" ::: "memory");                  \
        } else {                                                              \
            asm volatile("s_waitcnt vmcnt(0)" ::: "memory");                  \
        }                                                                     \
        __builtin_amdgcn_s_barrier();                                         \
        __builtin_amdgcn_sched_barrier(0);                                    \
        float z[4][4];                                                        \
        _Pragma("unroll")                                                     \
        for (int nk = 0; nk < 4; ++nk) {                                      \
            const unsigned short* krow = &Ks[CUR][16*nk + c][0];              \
            bf16x8 kh0 = *(const bf16x8*)(krow + (((quad     ) ^ cswz) << 3));\
            bf16x8 kh1 = *(const bf16x8*)(krow + (((quad +  4) ^ cswz) << 3));\
            bf16x8 kl0 = *(const bf16x8*)(krow + (((quad +  8) ^ cswz) << 3));\
            bf16x8 kl1 = *(const bf16x8*)(krow + (((quad + 12) ^ cswz) << 3));\
            float4 d4 = *(const float4*)&dwL[(KT) + nk*16 + quad*4];          \
            floatx4 s = {0.f,0.f,0.f,0.f};                                    \
            __builtin_amdgcn_s_setprio(1);                                    \
            s = MFMA16(kh0, qhi[0], s);                                       \
            s = MFMA16(kh1, qhi[1], s);                                       \
            s = MFMA16(kh0, qlo[0], s);                                       \
            s = MFMA16(kh1, qlo[1], s);                                       \
            s = MFMA16(kl0, qhi[0], s);                                       \
            s = MFMA16(kl1, qhi[1], s);                                       \
            __builtin_amdgcn_s_setprio(0);                                    \
            z[nk][0] = s[0] * d4.x;                                           \
            z[nk][1] = s[1] * d4.y;                                           \
            z[nk][2] = s[2] * d4.z;                                           \
            z[nk][3] = s[3] * d4.w;                                           \
        }                                                                     \
        {                                                                     \
            float tm = z[0][0];                                               \
            _Pragma("unroll")                                                 \
            for (int nk = 0; nk < 4; ++nk)                                    \
                _Pragma("unroll")                                             \
                for (int r = 0; r < 4; ++r) tm = fmaxf(tm, z[nk][r]);         \
            tm = fmaxf(tm, __shfl_xor(tm, 16));                               \
            tm = fmaxf(tm, __shfl_xor(tm, 32));                               \
            if (__any(tm > mrun)) {                                           \
                float mn = fmaxf(mrun, tm);                                   \
                float al = fexp2(mrun - mn);                                  \
                mrun = mn;                                                    \
                lrun *= al;                                                   \
                _Pragma("unroll")                                             \
                for (int nd = 0; nd < 4; ++nd)                                \
                    _Pragma("unroll")                                         \
                    for (int r = 0; r < 4; ++r)                               \
                        Oa[nd][r] *= al;                                      \
            }                                                                 \
            float rsum = 0.f;                                                 \
            _Pragma("unroll")                                                 \
            for (int nk = 0; nk < 4; ++nk)                                    \
                _Pragma("unroll")                                             \
                for (int r = 0; r < 4; ++r) {                                 \
                    z[nk][r] = fexp2(z[nk][r] - mrun);                        \
                    rsum += z[nk][r];                                         \
                }                                                             \
            rsum += __shfl_xor(rsum, 16);                                     \
            rsum += __shfl_xor(rsum, 32);                                     \
            lrun += rsum;                                                     \
        }                                                                     \
        bf16x4 pb[4];                                                         \
        _Pragma("unroll")                                                     \
        for (int nk = 0; nk < 4; ++nk)                                        \
            pb[nk] = pack_bf16x4(z[nk][0], z[nk][1], z[nk][2], z[nk][3]);     \
        __builtin_amdgcn_s_setprio(1);                                        \
        _Pragma("unroll")                                                     \
        for (int ks = 0; ks < 4; ++ks) {                                      \
            const int vch = ((2*ks + (quad >> 1)) ^ cswz);                    \
            _Pragma("unroll")                                                 \
            for (int nd = 0; nd < 4; ++nd) {                                  \
                const bf16x4 va = *(const bf16x4*)                            \
                    (&Vs[CUR][nd*16 + c][0] + (vch << 3) + ((quad & 1) << 2));\
                Oa[nd] = pv_mfma(va, pb[ks], Oa[nd]);                         \
            }                                                                 \
        }                                                                     \
        __builtin_amdgcn_s_setprio(0);                                        \
    }

    // SEQ/64 = 32 tiles, even -> clean x2 unroll with static buffer index.
    for (int kt = 0; kt < SEQ; kt += 128) {
        FLASH_TILE(0, kt, 1)
        FLASH_TILE(1, kt + 64, kt + 128 < SEQ)
    }
#undef FLASH_TILE

    {
        float invl = 1.f / lrun;
        int s_abs = qbase + wv*16 + c;
        unsigned short* orow = o + ((size_t)(b*SEQ + s_abs))*DIM + h*HDIM;
#pragma unroll
        for (int nd = 0; nd < 4; ++nd) {
            ushort4 o4;
            o4.x = f2bf(Oa[nd][0] * invl);
            o4.y = f2bf(Oa[nd][1] * invl);
            o4.z = f2bf(Oa[nd][2] * invl);
            o4.w = f2bf(Oa[nd][3] * invl);
            *(ushort4*)(orow + nd*16 + quad*4) = o4;
        }
    }
}

// ---------------------------------------------------------------------------
extern "C" void kernel_launch(void* const* d_in, const int* in_sizes, int n_in,
                              void* d_out, int out_size, void* d_ws, size_t ws_size,
                              hipStream_t stream)
{
    (void)in_sizes; (void)n_in; (void)out_size; (void)ws_size;
    const float* qi     = (const float*)d_in[0];
    const float* ki     = (const float*)d_in[1];
    const float* vi     = (const float*)d_in[2];
    const float* Wq     = (const float*)d_in[3];
    const float* Wq_def = (const float*)d_in[4];
    const float* Wk     = (const float*)d_in[5];
    const float* Wk_def = (const float*)d_in[6];
    const float* Wv     = (const float*)d_in[7];
    const float* Wo     = (const float*)d_in[8];
    float* out = (float*)d_out;

    char* ws = (char*)d_ws;
    const size_t MB = 1024 * 1024;
    // def phase (fp16):
    unsigned short* Aqf  = (unsigned short*)(ws +  0*MB);  // fp16 qi, 8 MB
    unsigned short* Akf  = (unsigned short*)(ws +  8*MB);  // fp16 ki, 8 MB
    unsigned short* Bqdf = (unsigned short*)(ws + 16*MB);  // fp16 Wq_def, 2 MB
    unsigned short* Bkdf = (unsigned short*)(ws + 18*MB);  // fp16 Wk_def, 2 MB
    unsigned short* qdf  = (unsigned short*)(ws + 20*MB);  // [32bh][2048][64] fp16, 8 MB
    unsigned short* kdf  = (unsigned short*)(ws + 28*MB);  // 8 MB
    // main phase (overwrites def phase after defw):
    unsigned short* Aq  = (unsigned short*)(ws +  0*MB);   // [4096][2048] hi|lo, 16 MB
    unsigned short* Ak  = (unsigned short*)(ws + 16*MB);   // 16 MB
    unsigned short* Bq  = (unsigned short*)(ws + 32*MB);   // 4 MB
    unsigned short* Bk  = (unsigned short*)(ws + 36*MB);   // 4 MB
    unsigned short* qs  = (unsigned short*)(ws + 40*MB);   // [32bh][2048][128] swz, 16 MB
    unsigned short* ks  = (unsigned short*)(ws + 56*MB);   // 16 MB
    float*          dw  = (float*)(ws + 72*MB);            // 256 KB (lives to flash)
    // phase 2 overlays (Aq/Ak/Bq/Bk dead):
    unsigned short* Av  = (unsigned short*)(ws +  0*MB);   // 8 MB
    unsigned short* Bv  = (unsigned short*)(ws +  8*MB);   // 2 MB
    unsigned short* Bo  = (unsigned short*)(ws + 10*MB);   // 2 MB
    unsigned short* Vt  = (unsigned short*)(ws + 12*MB);   // [32bh][64][2048] swz, 8 MB
    unsigned short* att = (unsigned short*)(ws + 20*MB);   // [4096][1024] bf16, 8 MB

    dim3 cb(256);
    dim3 gP(DIM/128, MR/128, 2);    // (8, 32, 2)
    dim3 gS(DIM/128, MR/128, 1);
    dim3 gA(SEQ/128, BSZ*NH);       // (16, 32) — Q-tile 128

    // 1. fp16 converts for the defeasible path
    conv_f16<<<dim3(4096, 4), cb, 0, stream>>>(
        qi, ki, Wq_def, Wk_def, Aqf, Akf, Bqdf, Bkdf, MR, MR, DIM, DIM);
    // 2. q_def, k_def (plain fp16 GEMM) -> [bh][s][64] fp16
    gemm_mfma<3, false, 1><<<gP, cb, 0, stream>>>(Aqf, Akf, Bqdf, Bkdf, qdf, kdf, 1024, 1024, 16);
    // 3. defeasible weights (pre-scaled by 0.125*log2e), 512 threads
    defw_mfma<<<gA, dim3(512), 0, stream>>>(qdf, kdf, dw);
    // 4. split-bf16 converts for the main path (overwrites def buffers)
    conv_split<<<dim3(4096, 4), cb, 0, stream>>>(
        qi, ki, Wq, Wk, Aq, Ak, Bq, Bk, MR, MR, DIM, DIM);
    // 5. q, k (split-3 bf16 GEMM) -> split-bh swizzled layout
    gemm_mfma<1, true, 0><<<gP, cb, 0, stream>>>(Aq, Ak, Bq, Bk, qs, ks, 2048, 2048, 48);
    // 6. hi converts for v path (Aq/Ak dead)
    conv_hi<<<dim3(4096, 3), cb, 0, stream>>>(vi, Wv, Wo, Av, Bv, Bo,
                                              MR*DIM, DIM*DIM, DIM*DIM);
    // 7. v projection -> V^T swizzled layout
    gemm_mfma<2, false, 0><<<gS, cb, 0, stream>>>(Av, Av, Bv, Bv, Vt, Vt, 1024, 1024, 16);
    // 8. attention (512 threads / 8 waves)
    flash_mfma<<<gA, dim3(512), 0, stream>>>(qs, ks, Vt, dw, att);
    // 9. output projection
    gemm_mfma<0, false, 0><<<gS, cb, 0, stream>>>(att, att, Bo, Bo, out, out, 1024, 1024, 16);
}

// Round 12
// 416.556 us; speedup vs baseline: 1.0674x; 1.0674x over previous
//
#include <hip/hip_runtime.h>
#include <math.h>

#define BSZ 2
#define SEQ 2048
#define DIM 1024
#define NH 16
#define HDIM 64
#define MR (BSZ*SEQ)   // 4096 rows

typedef __attribute__((ext_vector_type(8))) short bf16x8;
typedef __attribute__((ext_vector_type(4))) short bf16x4;
typedef __attribute__((ext_vector_type(4))) float floatx4;
typedef _Float16 f16x8 __attribute__((ext_vector_type(8)));

static __device__ __forceinline__ unsigned short f2bf(float x) {
    unsigned u = __float_as_uint(x);
    u += 0x7fffu + ((u >> 16) & 1u);
    return (unsigned short)(u >> 16);
}
static __device__ __forceinline__ float bf2f(unsigned short h) {
    return __uint_as_float(((unsigned)h) << 16);
}
static __device__ __forceinline__ unsigned short f2h(float x) {
    union { _Float16 h; unsigned short u; } v;
    v.h = (_Float16)x;
    return v.u;
}
// raw v_exp_f32 (exp2) — exp2f() is an OCML libcall with range fixups (VALU-heavy)
static __device__ __forceinline__ float fexp2(float x) {
#if __has_builtin(__builtin_amdgcn_exp2f)
    return __builtin_amdgcn_exp2f(x);
#else
    return __expf(x * 0.69314718055994531f);
#endif
}
// pack 4 f32 -> bf16x4 via v_cvt_pk_bf16_f32 (RNE), 2 VALU insts vs ~16 manual
static __device__ __forceinline__ bf16x4 pack_bf16x4(float a, float b, float c, float d) {
    union { unsigned u[2]; bf16x4 v; } r;
    asm("v_cvt_pk_bf16_f32 %0, %1, %2" : "=v"(r.u[0]) : "v"(a), "v"(b));
    asm("v_cvt_pk_bf16_f32 %0, %1, %2" : "=v"(r.u[1]) : "v"(c), "v"(d));
    return r.v;
}
#define MFMA16(a,b,c) __builtin_amdgcn_mfma_f32_16x16x32_bf16((a),(b),(c),0,0,0)

static __device__ __forceinline__ floatx4 mfma_f16(bf16x8 a, bf16x8 b, floatx4 c) {
    union { bf16x8 s; f16x8 h; } ua, ub;
    ua.s = a; ub.s = b;
    return __builtin_amdgcn_mfma_f32_16x16x32_f16(ua.h, ub.h, c, 0, 0, 0);
}

// 16x16x16 bf16 MFMA (K=16): A,B = 4 bf16/lane at k=quad*4+j.
static __device__ __forceinline__ floatx4 pv_mfma(bf16x4 a, bf16x4 b, floatx4 c) {
#if __has_builtin(__builtin_amdgcn_mfma_f32_16x16x16bf16_1k)
    return __builtin_amdgcn_mfma_f32_16x16x16bf16_1k(a, b, c, 0, 0, 0);
#else
    bf16x8 a8 = {a[0],a[1],a[2],a[3],0,0,0,0};
    bf16x8 b8 = {b[0],b[1],b[2],b[3],0,0,0,0};
    return MFMA16(a8, b8, c);
#endif
}

// async global -> LDS, 16 B per lane. LDS dest = wave-uniform base + lane*16.
static __device__ __forceinline__ void gld16(const void* g, void* l) {
    __builtin_amdgcn_global_load_lds(
        (const __attribute__((address_space(1))) void*)g,
        (__attribute__((address_space(3))) void*)l, 16, 0, 0);
}

// ---------------------------------------------------------------------------
// conv_split: fp32 [rows][1024] -> bf16 [rows][2048] as [hi | lo]
// ---------------------------------------------------------------------------
__global__ __launch_bounds__(256)
void conv_split(const float* p0, const float* p1, const float* p2,
                const float* p3,
                unsigned short* o0, unsigned short* o1, unsigned short* o2,
                unsigned short* o3,
                int r0, int r1, int r2, int r3)
{
    const float* pin; unsigned short* pout; int rows;
    switch (blockIdx.y) {
        case 0: pin=p0; pout=o0; rows=r0; break;
        case 1: pin=p1; pout=o1; rows=r1; break;
        case 2: pin=p2; pout=o2; rows=r2; break;
        default: pin=p3; pout=o3; rows=r3; break;
    }
    size_t idx = (size_t)blockIdx.x * 256 + threadIdx.x;   // group of 4 floats
    if (idx * 4 >= (size_t)rows * DIM) return;
    size_t row = (idx * 4) >> 10;
    int col = (int)((idx * 4) & 1023);
    float4 f = *(const float4*)(pin + idx * 4);
    ushort4 h, l;
    h.x = f2bf(f.x); l.x = f2bf(f.x - bf2f(h.x));
    h.y = f2bf(f.y); l.y = f2bf(f.y - bf2f(h.y));
    h.z = f2bf(f.z); l.z = f2bf(f.z - bf2f(h.z));
    h.w = f2bf(f.w); l.w = f2bf(f.w - bf2f(h.w));
    *(ushort4*)(pout + row * 2048 + col)        = h;
    *(ushort4*)(pout + row * 2048 + 1024 + col) = l;
}

// conv_f16: fp32 flat -> fp16 flat, 4 matrices via blockIdx.y
__global__ __launch_bounds__(256)
void conv_f16(const float* p0, const float* p1, const float* p2, const float* p3,
              unsigned short* o0, unsigned short* o1, unsigned short* o2,
              unsigned short* o3, int r0, int r1, int r2, int r3)
{
    const float* pin; unsigned short* pout; int rows;
    switch (blockIdx.y) {
        case 0: pin=p0; pout=o0; rows=r0; break;
        case 1: pin=p1; pout=o1; rows=r1; break;
        case 2: pin=p2; pout=o2; rows=r2; break;
        default: pin=p3; pout=o3; rows=r3; break;
    }
    size_t idx = (size_t)blockIdx.x * 256 + threadIdx.x;
    if (idx * 4 >= (size_t)rows * DIM) return;
    float4 f = *(const float4*)(pin + idx * 4);
    ushort4 h;
    h.x = f2h(f.x); h.y = f2h(f.y); h.z = f2h(f.z); h.w = f2h(f.w);
    *(ushort4*)(pout + idx * 4) = h;
}

// conv_hi: fp32 flat -> bf16 flat (hi only), 3 matrices via blockIdx.y
__global__ __launch_bounds__(256)
void conv_hi(const float* p0, const float* p1, const float* p2,
             unsigned short* o0, unsigned short* o1, unsigned short* o2,
             int n0, int n1, int n2)
{
    const float* pin; unsigned short* pout; int n;
    switch (blockIdx.y) {
        case 0: pin=p0; pout=o0; n=n0; break;
        case 1: pin=p1; pout=o1; n=n1; break;
        default: pin=p2; pout=o2; n=n2; break;
    }
    size_t idx = (size_t)blockIdx.x * 256 + threadIdx.x;
    if (idx * 4 >= (size_t)n) return;
    float4 f = *(const float4*)(pin + idx * 4);
    ushort4 h;
    h.x = f2bf(f.x); h.y = f2bf(f.y); h.z = f2bf(f.z); h.w = f2bf(f.w);
    *(ushort4*)(pout + idx * 4) = h;
}

// ---------------------------------------------------------------------------
// MFMA GEMM (verified round-8 body: reg-staged prefetch double-buffer —
// global loads for tile k+1 in flight during tile k's MFMA compute).
// DT: 0 = bf16 MFMA, 1 = fp16 MFMA.
// EPI: 0 = fp32 row-major [.][1024]
//      1 = split-bf16 per-(b,h): out[bh][s][0..63 hi | 64..127 lo],
//          16B-chunk XOR-swizzled by (s&7)   <-- for flash global_load_lds
//      2 = V^T per-(b,h): out[bh][d][s] (bf16), 16B-chunk swizzled by (d&7)
//      3 = fp16 per-bh: out[bh][s][d] (fp16)
// ---------------------------------------------------------------------------
template<int EPI, bool SPLIT3, int DT>
__global__ __launch_bounds__(256)
void gemm_mfma(const unsigned short* __restrict__ A0, const unsigned short* __restrict__ A1,
               const unsigned short* __restrict__ B0, const unsigned short* __restrict__ B1,
               void* C0v, void* C1v, int lda, int ldb, int nkb)
{
    const unsigned short* A = blockIdx.z ? A1 : A0;
    const unsigned short* B = blockIdx.z ? B1 : B0;
    float* Cf = (float*)(blockIdx.z ? C1v : C0v);
    unsigned short* Cb = (unsigned short*)(blockIdx.z ? C1v : C0v);

    __shared__ __align__(16) unsigned short As[128][72];
    __shared__ __align__(16) unsigned short Bs[128][72];

    const int tid = threadIdx.x;
    const int lane = tid & 63, wv = tid >> 6;
    const int c = lane & 15, quad = lane >> 4;
    const int wm = wv >> 1, wn = wv & 1;
    const int rowBase = blockIdx.y << 7;
    const int colBase = blockIdx.x << 7;

    floatx4 acc[4][4];
#pragma unroll
    for (int i = 0; i < 4; ++i)
#pragma unroll
        for (int j = 0; j < 4; ++j) acc[i][j] = (floatx4){0.f,0.f,0.f,0.f};

    bf16x8 ar[4], br[4];
    {
#pragma unroll
        for (int i = 0; i < 4; ++i) {
            int f = tid + (i << 8);
            int r = f >> 3, kbk = (f & 7) << 3;
            ar[i] = *(const bf16x8*)(A + (size_t)(rowBase + r) * lda + kbk);
            br[i] = *(const bf16x8*)(B + (size_t)(colBase + r) * ldb + kbk);
        }
    }
    for (int kb = 0; kb < nkb; ++kb) {
        __syncthreads();
#pragma unroll
        for (int i = 0; i < 4; ++i) {
            int f = tid + (i << 8);
            int r = f >> 3, kbk = (f & 7) << 3;
            *(bf16x8*)&As[r][kbk] = ar[i];
            *(bf16x8*)&Bs[r][kbk] = br[i];
        }
        __syncthreads();
        if (kb + 1 < nkb) {
            int kn = kb + 1, aoff, boff;
            if (SPLIT3) {
                int t = kn >> 4, kk = (kn & 15) << 6;
                aoff = ((t == 1) ? 1024 : 0) + kk;
                boff = ((t == 2) ? 1024 : 0) + kk;
            } else { aoff = boff = kn << 6; }
#pragma unroll
            for (int i = 0; i < 4; ++i) {
                int f = tid + (i << 8);
                int r = f >> 3, kbk = (f & 7) << 3;
                ar[i] = *(const bf16x8*)(A + (size_t)(rowBase + r) * lda + aoff + kbk);
                br[i] = *(const bf16x8*)(B + (size_t)(colBase + r) * ldb + boff + kbk);
            }
        }
#pragma unroll
        for (int ks = 0; ks < 2; ++ks) {
            bf16x8 af[4], bfr[4];
#pragma unroll
            for (int i = 0; i < 4; ++i) {
                af[i]  = *(const bf16x8*)&As[wm*64 + i*16 + c][ks*32 + quad*8];
                bfr[i] = *(const bf16x8*)&Bs[wn*64 + i*16 + c][ks*32 + quad*8];
            }
#pragma unroll
            for (int mi = 0; mi < 4; ++mi)
#pragma unroll
                for (int ni = 0; ni < 4; ++ni) {
                    if (DT == 0) acc[mi][ni] = MFMA16(af[mi], bfr[ni], acc[mi][ni]);
                    else         acc[mi][ni] = mfma_f16(af[mi], bfr[ni], acc[mi][ni]);
                }
        }
    }
    const int row0 = rowBase + wm*64 + quad*4;
    if (EPI == 0) {
        const int col0 = colBase + wn*64 + c;
#pragma unroll
        for (int mi = 0; mi < 4; ++mi)
#pragma unroll
            for (int r = 0; r < 4; ++r) {
                size_t ro = (size_t)(row0 + mi*16 + r) * 1024 + col0;
#pragma unroll
                for (int ni = 0; ni < 4; ++ni)
                    Cf[ro + ni*16] = acc[mi][ni][r];
            }
    } else if (EPI == 1) {
        const int h = (colBase >> 6) + wn;       // head index
#pragma unroll
        for (int mi = 0; mi < 4; ++mi)
#pragma unroll
            for (int r = 0; r < 4; ++r) {
                int row = row0 + mi*16 + r;
                int b = row >> 11, s = row & 2047;
                size_t base = ((size_t)((b<<4) | h) * 2048 + s) * 128;
                const int sw = (s & 7) << 3;     // chunk-XOR in element units
#pragma unroll
                for (int ni = 0; ni < 4; ++ni) {
                    int d = ni*16 + c;
                    int dsw = d ^ sw;            // swizzled hi position (bit6 untouched)
                    float x = acc[mi][ni][r];
                    unsigned short hb = f2bf(x);
                    Cb[base + dsw]      = hb;
                    Cb[base + 64 + dsw] = f2bf(x - bf2f(hb));
                }
            }
    } else if (EPI == 2) {  // Vt[bh][d][s], 16B chunks along s swizzled by (d&7)
        const int h = (colBase >> 6) + wn;
#pragma unroll
        for (int mi = 0; mi < 4; ++mi) {
            int row = row0 + mi*16;
            int b = row >> 11, s = row & 2047;
#pragma unroll
            for (int ni = 0; ni < 4; ++ni) {
                int d = ni*16 + c;
                int scol = s ^ ((d & 7) << 3);   // s%8 in {0,4}: stays inside chunk
                size_t base = ((size_t)((b<<4)|h) * 64 + d) * 2048 + scol;
                ushort4 o4;
                o4.x = f2bf(acc[mi][ni][0]); o4.y = f2bf(acc[mi][ni][1]);
                o4.z = f2bf(acc[mi][ni][2]); o4.w = f2bf(acc[mi][ni][3]);
                *(ushort4*)(Cb + base) = o4;
            }
        }
    } else {  // EPI == 3: fp16 per-bh [bh][s][64]
        const int h = (colBase >> 6) + wn;
#pragma unroll
        for (int mi = 0; mi < 4; ++mi)
#pragma unroll
            for (int r = 0; r < 4; ++r) {
                int row = row0 + mi*16 + r;
                int b = row >> 11, s = row & 2047;
                size_t base = ((size_t)((b<<4) | h) * 2048 + s) * 64;
#pragma unroll
                for (int ni = 0; ni < 4; ++ni)
                    Cb[base + ni*16 + c] = f2h(acc[mi][ni][r]);
            }
    }
}

// ---------------------------------------------------------------------------
// def_w, fp16: qd/kd are [bh][s][64] fp16. 512 threads / 8 waves, 16 q-rows
// per wave (verified correct in round 10; occupancy transform mirrors the
// +15% flash win). Keeps reg-staged K prefetch. Writes def_w * 0.125*log2e.
// ---------------------------------------------------------------------------
__global__ __launch_bounds__(512)
void defw_mfma(const unsigned short* __restrict__ qd,
               const unsigned short* __restrict__ kd,
               float* __restrict__ defw)
{
    __shared__ __align__(16) unsigned short Ks[64][72];
    const int tid = threadIdx.x;
    const int wv = tid >> 6, lane = tid & 63;
    const int c = lane & 15, quad = lane >> 4;
    const int bh = blockIdx.y;
    const int qbase = blockIdx.x << 7;
    const int trow = tid >> 3, seg = tid & 7;   // 64 rows x 8 chunks

    bf16x8 qf[2];
    {
        const unsigned short* qrow =
            qd + ((size_t)bh*2048 + qbase + wv*16 + c)*64 + quad*8;
        qf[0] = *(const bf16x8*)(qrow);
        qf[1] = *(const bf16x8*)(qrow + 32);
    }
    float rs[4] = {0.f,0.f,0.f,0.f};
    const unsigned short* kbase = kd + (size_t)bh*2048*64;
    bf16x8 kpre = *(const bf16x8*)(kbase + (size_t)trow*64 + seg*8);
    for (int kt = 0; kt < SEQ; kt += 64) {
        __syncthreads();
        *(bf16x8*)&Ks[trow][seg*8] = kpre;
        __syncthreads();
        if (kt + 64 < SEQ)
            kpre = *(const bf16x8*)(kbase + (size_t)(kt + 64 + trow)*64 + seg*8);
#pragma unroll
        for (int nk = 0; nk < 4; ++nk) {
            const unsigned short* kr = &Ks[16*nk + c][quad*8];
            bf16x8 k0 = *(const bf16x8*)(kr);
            bf16x8 k1 = *(const bf16x8*)(kr + 32);
            floatx4 s = {0.f,0.f,0.f,0.f};
            s = mfma_f16(qf[0], k0, s);
            s = mfma_f16(qf[1], k1, s);
#pragma unroll
            for (int r = 0; r < 4; ++r)
                rs[r] += 1.f / (1.f + __expf(-0.125f * s[r]));
        }
    }
#pragma unroll
    for (int r = 0; r < 4; ++r) {
        float vv = rs[r];
        vv += __shfl_xor(vv, 1, 16);
        vv += __shfl_xor(vv, 2, 16);
        vv += __shfl_xor(vv, 4, 16);
        vv += __shfl_xor(vv, 8, 16);
        if (c == 0)
            defw[(size_t)bh*SEQ + qbase + wv*16 + 4*quad + r]
                = vv * 0.18033688011112042f;   // 0.125 * log2(e)
    }
}

// ---------------------------------------------------------------------------
// Flash attention (verified round-8: 99.2 us): 8 waves / 512 threads,
// 16 q-rows/wave. K/V via global_load_lds double-buffered, counted vmcnt(3),
// x2-unrolled K-loop with compile-time buffer index, setprio around MFMA.
// ---------------------------------------------------------------------------
__global__ __launch_bounds__(512)
void flash_mfma(const unsigned short* __restrict__ q,
                const unsigned short* __restrict__ kk,
                const unsigned short* __restrict__ vt,
                const float* __restrict__ dwg,
                unsigned short* __restrict__ o)
{
    __shared__ __align__(16) unsigned short Ks[2][64][128];  // 32 KB
    __shared__ __align__(16) unsigned short Vs[2][64][64];   // 16 KB
    __shared__ __align__(16) float dwL[SEQ];                 //  8 KB
    const int tid = threadIdx.x;
    const int wv = tid >> 6, lane = tid & 63;
    const int c = lane & 15, quad = lane >> 4;
    const int cswz = c & 7;
    const int bh = blockIdx.y, b = bh >> 4, h = bh & 15;
    const int qbase = blockIdx.x << 7;

    const unsigned short* kbase = kk + (size_t)bh*2048*128;
    const unsigned short* vbase = vt + (size_t)bh*64*2048;

    // ---- prologue: Q fragments (swizzled global layout), 16 rows/wave ----
    bf16x8 qhi[2], qlo[2];
    {
        const unsigned short* qrow =
            q + ((size_t)bh*2048 + qbase + wv*16 + c)*128;
        qhi[0] = *(const bf16x8*)(qrow + (((quad     ) ^ cswz) << 3));
        qhi[1] = *(const bf16x8*)(qrow + (((quad +  4) ^ cswz) << 3));
        qlo[0] = *(const bf16x8*)(qrow + (((quad +  8) ^ cswz) << 3));
        qlo[1] = *(const bf16x8*)(qrow + (((quad + 12) ^ cswz) << 3));
    }
    // dw row -> LDS (512 thr x 16B = 8 KB, 1 DMA inst / thread)
    gld16(dwg + (size_t)bh*SEQ + (size_t)tid*4, &dwL[(wv*64) * 4]);
    // tile 0 -> buffer 0 (K: 2/thread, V: 1/thread)
#pragma unroll
    for (int i = 0; i < 2; ++i) {
        int flat = tid + (i << 9);
        int r = flat >> 4, ch = flat & 15;
        gld16(kbase + (size_t)r*128 + (ch << 3),
              &Ks[0][0][0] + ((wv*64 + (i << 9)) << 3));
    }
    {
        int d = tid >> 3, ch = tid & 7;
        gld16(vbase + (size_t)d*2048 + (ch << 3),
              &Vs[0][0][0] + (wv*64 << 3));
    }

    floatx4 Oa[4];    // [nd], O^T[d][s]
#pragma unroll
    for (int nd = 0; nd < 4; ++nd) Oa[nd] = (floatx4){0.f,0.f,0.f,0.f};
    float mrun = -3.0e38f, lrun = 0.f;

// One 64-row K/V tile with compile-time buffer index CUR.
// PF: prefetch next tile into buffer CUR^1 (counted vmcnt keeps the 3 new
// loads in flight; vmcnt(3) drains the PREVIOUS tile's 3).
#define FLASH_TILE(CUR, KT, PF)                                               \
    {                                                                         \
        __builtin_amdgcn_s_barrier();                                         \
        if (PF) {                                                             \
            _Pragma("unroll")                                                 \
            for (int i = 0; i < 2; ++i) {                                     \
                int flat = tid + (i << 9);                                    \
                int r = flat >> 4, ch = flat & 15;                            \
                gld16(kbase + (size_t)((KT) + 64 + r)*128 + (ch << 3),        \
                      &Ks[(CUR)^1][0][0] + ((wv*64 + (i << 9)) << 3));        \
            }                                                                 \
            {                                                                 \
                int d = tid >> 3, ch = tid & 7;                               \
                gld16(vbase + (size_t)d*2048 + ((KT) + 64) + (ch << 3),       \
                      &Vs[(CUR)^1][0][0] + (wv*64 << 3));                     \
            }                                                                 \
            asm volatile("s_waitcnt vmcnt(3)" ::: "memory");                  \
        } else {                                                              \
            asm volatile("s_waitcnt vmcnt(0)" ::: "memory");                  \
        }                                                                     \
        __builtin_amdgcn_s_barrier();                                         \
        __builtin_amdgcn_sched_barrier(0);                                    \
        float z[4][4];                                                        \
        _Pragma("unroll")                                                     \
        for (int nk = 0; nk < 4; ++nk) {                                      \
            const unsigned short* krow = &Ks[CUR][16*nk + c][0];              \
            bf16x8 kh0 = *(const bf16x8*)(krow + (((quad     ) ^ cswz) << 3));\
            bf16x8 kh1 = *(const bf16x8*)(krow + (((quad +  4) ^ cswz) << 3));\
            bf16x8 kl0 = *(const bf16x8*)(krow + (((quad +  8) ^ cswz) << 3));\
            bf16x8 kl1 = *(const bf16x8*)(krow + (((quad + 12) ^ cswz) << 3));\
            float4 d4 = *(const float4*)&dwL[(KT) + nk*16 + quad*4];          \
            floatx4 s = {0.f,0.f,0.f,0.f};                                    \
            __builtin_amdgcn_s_setprio(1);                                    \
            s = MFMA16(kh0, qhi[0], s);                                       \
            s = MFMA16(kh1, qhi[1], s);                                       \
            s = MFMA16(kh0, qlo[0], s);                                       \
            s = MFMA16(kh1, qlo[1], s);                                       \
            s = MFMA16(kl0, qhi[0], s);                                       \
            s = MFMA16(kl1, qhi[1], s);                                       \
            __builtin_amdgcn_s_setprio(0);                                    \
            z[nk][0] = s[0] * d4.x;                                           \
            z[nk][1] = s[1] * d4.y;                                           \
            z[nk][2] = s[2] * d4.z;                                           \
            z[nk][3] = s[3] * d4.w;                                           \
        }                                                                     \
        {                                                                     \
            float tm = z[0][0];                                               \
            _Pragma("unroll")                                                 \
            for (int nk = 0; nk < 4; ++nk)                                    \
                _Pragma("unroll")                                             \
                for (int r = 0; r < 4; ++r) tm = fmaxf(tm, z[nk][r]);         \
            tm = fmaxf(tm, __shfl_xor(tm, 16));                               \
            tm = fmaxf(tm, __shfl_xor(tm, 32));                               \
            if (__any(tm > mrun)) {                                           \
                float mn = fmaxf(mrun, tm);                                   \
                float al = fexp2(mrun - mn);                                  \
                mrun = mn;                                                    \
                lrun *= al;                                                   \
                _Pragma("unroll")                                             \
                for (int nd = 0; nd < 4; ++nd)                                \
                    _Pragma("unroll")                                         \
                    for (int r = 0; r < 4; ++r)                               \
                        Oa[nd][r] *= al;                                      \
            }                                                                 \
            float rsum = 0.f;                                                 \
            _Pragma("unroll")                                                 \
            for (int nk = 0; nk < 4; ++nk)                                    \
                _Pragma("unroll")                                             \
                for (int r = 0; r < 4; ++r) {                                 \
                    z[nk][r] = fexp2(z[nk][r] - mrun);                        \
                    rsum += z[nk][r];                                         \
                }                                                             \
            rsum += __shfl_xor(rsum, 16);                                     \
            rsum += __shfl_xor(rsum, 32);                                     \
            lrun += rsum;                                                     \
        }                                                                     \
        bf16x4 pb[4];                                                         \
        _Pragma("unroll")                                                     \
        for (int nk = 0; nk < 4; ++nk)                                        \
            pb[nk] = pack_bf16x4(z[nk][0], z[nk][1], z[nk][2], z[nk][3]);     \
        __builtin_amdgcn_s_setprio(1);                                        \
        _Pragma("unroll")                                                     \
        for (int ks = 0; ks < 4; ++ks) {                                      \
            const int vch = ((2*ks + (quad >> 1)) ^ cswz);                    \
            _Pragma("unroll")                                                 \
            for (int nd = 0; nd < 4; ++nd) {                                  \
                const bf16x4 va = *(const bf16x4*)                            \
                    (&Vs[CUR][nd*16 + c][0] + (vch << 3) + ((quad & 1) << 2));\
                Oa[nd] = pv_mfma(va, pb[ks], Oa[nd]);                         \
            }                                                                 \
        }                                                                     \
        __builtin_amdgcn_s_setprio(0);                                        \
    }

    // SEQ/64 = 32 tiles, even -> clean x2 unroll with static buffer index.
    for (int kt = 0; kt < SEQ; kt += 128) {
        FLASH_TILE(0, kt, 1)
        FLASH_TILE(1, kt + 64, kt + 128 < SEQ)
    }
#undef FLASH_TILE

    {
        float invl = 1.f / lrun;
        int s_abs = qbase + wv*16 + c;
        unsigned short* orow = o + ((size_t)(b*SEQ + s_abs))*DIM + h*HDIM;
#pragma unroll
        for (int nd = 0; nd < 4; ++nd) {
            ushort4 o4;
            o4.x = f2bf(Oa[nd][0] * invl);
            o4.y = f2bf(Oa[nd][1] * invl);
            o4.z = f2bf(Oa[nd][2] * invl);
            o4.w = f2bf(Oa[nd][3] * invl);
            *(ushort4*)(orow + nd*16 + quad*4) = o4;
        }
    }
}

// ---------------------------------------------------------------------------
extern "C" void kernel_launch(void* const* d_in, const int* in_sizes, int n_in,
                              void* d_out, int out_size, void* d_ws, size_t ws_size,
                              hipStream_t stream)
{
    (void)in_sizes; (void)n_in; (void)out_size; (void)ws_size;
    const float* qi     = (const float*)d_in[0];
    const float* ki     = (const float*)d_in[1];
    const float* vi     = (const float*)d_in[2];
    const float* Wq     = (const float*)d_in[3];
    const float* Wq_def = (const float*)d_in[4];
    const float* Wk     = (const float*)d_in[5];
    const float* Wk_def = (const float*)d_in[6];
    const float* Wv     = (const float*)d_in[7];
    const float* Wo     = (const float*)d_in[8];
    float* out = (float*)d_out;

    char* ws = (char*)d_ws;
    const size_t MB = 1024 * 1024;
    // def phase (fp16):
    unsigned short* Aqf  = (unsigned short*)(ws +  0*MB);  // fp16 qi, 8 MB
    unsigned short* Akf  = (unsigned short*)(ws +  8*MB);  // fp16 ki, 8 MB
    unsigned short* Bqdf = (unsigned short*)(ws + 16*MB);  // fp16 Wq_def, 2 MB
    unsigned short* Bkdf = (unsigned short*)(ws + 18*MB);  // fp16 Wk_def, 2 MB
    unsigned short* qdf  = (unsigned short*)(ws + 20*MB);  // [32bh][2048][64] fp16, 8 MB
    unsigned short* kdf  = (unsigned short*)(ws + 28*MB);  // 8 MB
    // main phase (overwrites def phase after defw):
    unsigned short* Aq  = (unsigned short*)(ws +  0*MB);   // [4096][2048] hi|lo, 16 MB
    unsigned short* Ak  = (unsigned short*)(ws + 16*MB);   // 16 MB
    unsigned short* Bq  = (unsigned short*)(ws + 32*MB);   // 4 MB
    unsigned short* Bk  = (unsigned short*)(ws + 36*MB);   // 4 MB
    unsigned short* qs  = (unsigned short*)(ws + 40*MB);   // [32bh][2048][128] swz, 16 MB
    unsigned short* ks  = (unsigned short*)(ws + 56*MB);   // 16 MB
    float*          dw  = (float*)(ws + 72*MB);            // 256 KB (lives to flash)
    // phase 2 overlays (Aq/Ak/Bq/Bk dead):
    unsigned short* Av  = (unsigned short*)(ws +  0*MB);   // 8 MB
    unsigned short* Bv  = (unsigned short*)(ws +  8*MB);   // 2 MB
    unsigned short* Bo  = (unsigned short*)(ws + 10*MB);   // 2 MB
    unsigned short* Vt  = (unsigned short*)(ws + 12*MB);   // [32bh][64][2048] swz, 8 MB
    unsigned short* att = (unsigned short*)(ws + 20*MB);   // [4096][1024] bf16, 8 MB

    dim3 cb(256);
    dim3 gP(DIM/128, MR/128, 2);    // (8, 32, 2)
    dim3 gS(DIM/128, MR/128, 1);
    dim3 gA(SEQ/128, BSZ*NH);       // (16, 32) — Q-tile 128

    // 1. fp16 converts for the defeasible path
    conv_f16<<<dim3(4096, 4), cb, 0, stream>>>(
        qi, ki, Wq_def, Wk_def, Aqf, Akf, Bqdf, Bkdf, MR, MR, DIM, DIM);
    // 2. q_def, k_def (plain fp16 GEMM) -> [bh][s][64] fp16
    gemm_mfma<3, false, 1><<<gP, cb, 0, stream>>>(Aqf, Akf, Bqdf, Bkdf, qdf, kdf, 1024, 1024, 16);
    // 3. defeasible weights (pre-scaled by 0.125*log2e), 512 threads
    defw_mfma<<<gA, dim3(512), 0, stream>>>(qdf, kdf, dw);
    // 4. split-bf16 converts for the main path (overwrites def buffers)
    conv_split<<<dim3(4096, 4), cb, 0, stream>>>(
        qi, ki, Wq, Wk, Aq, Ak, Bq, Bk, MR, MR, DIM, DIM);
    // 5. q, k (split-3 bf16 GEMM) -> split-bh swizzled layout
    gemm_mfma<1, true, 0><<<gP, cb, 0, stream>>>(Aq, Ak, Bq, Bk, qs, ks, 2048, 2048, 48);
    // 6. hi converts for v path (Aq/Ak dead)
    conv_hi<<<dim3(4096, 3), cb, 0, stream>>>(vi, Wv, Wo, Av, Bv, Bo,
                                              MR*DIM, DIM*DIM, DIM*DIM);
    // 7. v projection -> V^T swizzled layout
    gemm_mfma<2, false, 0><<<gS, cb, 0, stream>>>(Av, Av, Bv, Bv, Vt, Vt, 1024, 1024, 16);
    // 8. attention (512 threads / 8 waves)
    flash_mfma<<<gA, dim3(512), 0, stream>>>(qs, ks, Vt, dw, att);
    // 9. output projection
    gemm_mfma<0, false, 0><<<gS, cb, 0, stream>>>(att, att, Bo, Bo, out, out, 1024, 1024, 16);
}